// Round 1
// baseline (4865.517 us; speedup 1.0000x reference)
//
#include <hip/hip_runtime.h>

// Seq2SeqDecoder: GRU + Bahdanau attention decoder, B=32 T=64 S=128
// Strategy R1: precompute everything h-independent (emb gather, enc_proj GEMM,
// emb-halves of gi and pred as batch GEMMs), then 64 serial steps of
// {step1: attention || pred(t-1)} + {step2: h_new}.

constexpr int BB  = 32;    // batch
constexpr int TT  = 64;    // decode steps
constexpr int SS  = 128;   // source length
constexpr int DD  = 768;   // embed dim
constexpr int EE  = 1024;  // encoder dim (E2)
constexpr int HH  = 512;   // hidden
constexpr int G3  = 1536;  // 3*H
constexpr int II  = 1792;  // E2 + D  (W_ih row length)
constexpr int CIN = 2304;  // H + E2 + D (fc_W row length)

__device__ __forceinline__ float fast_rcp(float x) { return __builtin_amdgcn_rcpf(x); }
// tanh(x) = 1 - 2/(1+exp(2x)); handles +-inf cleanly, ~1e-6 abs err
__device__ __forceinline__ float tanh_f(float x) {
  float e = __expf(2.f * x);
  return 1.f - 2.f * fast_rcp(1.f + e);
}
__device__ __forceinline__ float sigmoid_f(float x) {
  return fast_rcp(1.f + __expf(-x));
}

// ---------------- embedding gather: emb_all[b*T+t,:] = embed_W[id]*sqrt(D) ---
__global__ __launch_bounds__(256) void emb_kernel(
    const int* __restrict__ ids, const float* __restrict__ embed_W,
    float* __restrict__ emb_all)
{
  const int row = blockIdx.x;              // b*T + t
  const int id  = ids[row];                // attention_mask is all-ones
  const float scale = 27.712812921102035f; // sqrt(768)
  const float* src = embed_W + (size_t)id * DD;
  float* dst = emb_all + (size_t)row * DD;
  for (int c = threadIdx.x; c < DD; c += 256) dst[c] = src[c] * scale;
}

// ---------------- h_buf[parity=1] = enc_hidden -------------------------------
__global__ __launch_bounds__(512) void copyh_kernel(
    const float* __restrict__ src, float* __restrict__ h_buf)
{
  int i = blockIdx.x * 512 + threadIdx.x;
  if (i < BB * HH) h_buf[BB * HH + i] = src[i];
}

// ---------------- f32 tiled GEMMs (128x128x32, 256 thr, 8x8 microtile) -------
constexpr int BM = 128, BN = 128, BK = 32;

// C[M,N] = A[M,K](lda) @ B[K,N](ldb) + bias[N]
__global__ __launch_bounds__(256) void gemm_ab(
    const float* __restrict__ A, int lda,
    const float* __restrict__ Bm, int ldb,
    const float* __restrict__ bias,
    float* __restrict__ C, int ldc, int K)
{
  __shared__ float As[BK][BM + 4];
  __shared__ float Bs[BK][BN + 4];
  const int tid = threadIdx.x;
  const int m0 = blockIdx.y * BM, n0 = blockIdx.x * BN;
  const int a_m = tid >> 3, a_k = (tid & 7) << 2;
  const int b_k = tid >> 5, b_n = (tid & 31) << 2;
  const int tm = tid >> 4, tn = tid & 15;
  float acc[8][8] = {};
  for (int k0 = 0; k0 < K; k0 += BK) {
    float4 av[4], bv[4];
#pragma unroll
    for (int r = 0; r < 4; ++r)
      av[r] = *(const float4*)(A + (size_t)(m0 + a_m + 32 * r) * lda + k0 + a_k);
#pragma unroll
    for (int r = 0; r < 4; ++r)
      bv[r] = *(const float4*)(Bm + (size_t)(k0 + b_k + 8 * r) * ldb + n0 + b_n);
    __syncthreads();
#pragma unroll
    for (int r = 0; r < 4; ++r) {
      As[a_k + 0][a_m + 32 * r] = av[r].x;
      As[a_k + 1][a_m + 32 * r] = av[r].y;
      As[a_k + 2][a_m + 32 * r] = av[r].z;
      As[a_k + 3][a_m + 32 * r] = av[r].w;
      *(float4*)(&Bs[b_k + 8 * r][b_n]) = bv[r];
    }
    __syncthreads();
#pragma unroll
    for (int k = 0; k < BK; ++k) {
      float4 a0 = *(const float4*)(&As[k][tm * 8]);
      float4 a1 = *(const float4*)(&As[k][tm * 8 + 4]);
      float4 b0 = *(const float4*)(&Bs[k][tn * 8]);
      float4 b1 = *(const float4*)(&Bs[k][tn * 8 + 4]);
      const float ar[8] = {a0.x, a0.y, a0.z, a0.w, a1.x, a1.y, a1.z, a1.w};
      const float br[8] = {b0.x, b0.y, b0.z, b0.w, b1.x, b1.y, b1.z, b1.w};
#pragma unroll
      for (int i = 0; i < 8; ++i)
#pragma unroll
        for (int j = 0; j < 8; ++j)
          acc[i][j] = fmaf(ar[i], br[j], acc[i][j]);
    }
  }
#pragma unroll
  for (int i = 0; i < 8; ++i) {
    const int m = m0 + tm * 8 + i;
#pragma unroll
    for (int j = 0; j < 8; ++j) {
      const int n = n0 + tn * 8 + j;
      C[(size_t)m * ldc + n] = acc[i][j] + bias[n];
    }
  }
}

// C[M,N] = A[M,K](lda) @ Bt[N,K](ldb)^T + bias[N]
__global__ __launch_bounds__(256) void gemm_abt(
    const float* __restrict__ A, int lda,
    const float* __restrict__ Bt, int ldb,
    const float* __restrict__ bias,
    float* __restrict__ C, int ldc, int K)
{
  __shared__ float As[BK][BM + 4];
  __shared__ float Bs[BK][BN + 4];
  const int tid = threadIdx.x;
  const int m0 = blockIdx.y * BM, n0 = blockIdx.x * BN;
  const int a_m = tid >> 3, a_k = (tid & 7) << 2;
  const int t_n = tid >> 3, t_k = (tid & 7) << 2;
  const int tm = tid >> 4, tn = tid & 15;
  float acc[8][8] = {};
  for (int k0 = 0; k0 < K; k0 += BK) {
    float4 av[4], bv[4];
#pragma unroll
    for (int r = 0; r < 4; ++r)
      av[r] = *(const float4*)(A + (size_t)(m0 + a_m + 32 * r) * lda + k0 + a_k);
#pragma unroll
    for (int r = 0; r < 4; ++r)
      bv[r] = *(const float4*)(Bt + (size_t)(n0 + t_n + 32 * r) * ldb + k0 + t_k);
    __syncthreads();
#pragma unroll
    for (int r = 0; r < 4; ++r) {
      As[a_k + 0][a_m + 32 * r] = av[r].x;
      As[a_k + 1][a_m + 32 * r] = av[r].y;
      As[a_k + 2][a_m + 32 * r] = av[r].z;
      As[a_k + 3][a_m + 32 * r] = av[r].w;
      Bs[t_k + 0][t_n + 32 * r] = bv[r].x;
      Bs[t_k + 1][t_n + 32 * r] = bv[r].y;
      Bs[t_k + 2][t_n + 32 * r] = bv[r].z;
      Bs[t_k + 3][t_n + 32 * r] = bv[r].w;
    }
    __syncthreads();
#pragma unroll
    for (int k = 0; k < BK; ++k) {
      float4 a0 = *(const float4*)(&As[k][tm * 8]);
      float4 a1 = *(const float4*)(&As[k][tm * 8 + 4]);
      float4 b0 = *(const float4*)(&Bs[k][tn * 8]);
      float4 b1 = *(const float4*)(&Bs[k][tn * 8 + 4]);
      const float ar[8] = {a0.x, a0.y, a0.z, a0.w, a1.x, a1.y, a1.z, a1.w};
      const float br[8] = {b0.x, b0.y, b0.z, b0.w, b1.x, b1.y, b1.z, b1.w};
#pragma unroll
      for (int i = 0; i < 8; ++i)
#pragma unroll
        for (int j = 0; j < 8; ++j)
          acc[i][j] = fmaf(ar[i], br[j], acc[i][j]);
    }
  }
#pragma unroll
  for (int i = 0; i < 8; ++i) {
    const int m = m0 + tm * 8 + i;
#pragma unroll
    for (int j = 0; j < 8; ++j) {
      const int n = n0 + tn * 8 + j;
      C[(size_t)m * ldc + n] = acc[i][j] + bias[n];
    }
  }
}

// ---------------- step1: blocks 0..31 attention(t); blocks 32..223 pred(t-1) -
__global__ __launch_bounds__(512) void step1_kernel(
    int t,
    const float* __restrict__ attn_W,      // (1536, 512): rows 0..511 = Wa_h
    const float* __restrict__ val_w,       // (512)
    const float* __restrict__ enc_outputs, // (B,S,E2)
    const float* __restrict__ enc_proj,    // (B,S,H), includes attn_b
    const float* __restrict__ fc_W,        // (768, 2304)
    float* __restrict__ h_buf,             // 2 x (B,H)
    float* __restrict__ wtd_buf,           // 2 x (B,E2)
    float* __restrict__ out)               // (B,T,D), pred_emb already there
{
  __shared__ float hs[HH];
  __shared__ float hwa[HH];
  __shared__ float sc[SS];
  __shared__ float red2[2];
  const int tid = threadIdx.x;
  const int bid = blockIdx.x;
  const int pp = (t & 1) ^ 1;  // parity holding h(t-1)

  if (bid < BB) {
    if (t >= TT) return;
    const int b = bid;
    const float* hp = h_buf + (size_t)pp * (BB * HH) + (size_t)b * HH;
    hs[tid] = hp[tid];
    __syncthreads();
    // hWa[j] = sum_i h[i] * Wa_h[i, j]
    {
      float acc = 0.f;
#pragma unroll 8
      for (int i = 0; i < HH; ++i)
        acc = fmaf(hs[i], attn_W[i * HH + tid], acc);
      hwa[tid] = acc;
    }
    __syncthreads();
    // scores[s] = sum_j tanh(enc_proj[b,s,j] + hWa[j]) * val_w[j]
    {
      const int s_ = tid >> 2, q = tid & 3;
      const float* ep = enc_proj + ((size_t)b * SS + s_) * HH;
      float a0 = 0.f;
#pragma unroll 4
      for (int j = q; j < HH; j += 4)
        a0 = fmaf(tanh_f(ep[j] + hwa[j]), val_w[j], a0);
      a0 += __shfl_xor(a0, 1);
      a0 += __shfl_xor(a0, 2);
      if (q == 0) sc[s_] = a0;
    }
    __syncthreads();
    if (tid < 64) {
      float v = fmaxf(sc[tid], sc[tid + 64]);
#pragma unroll
      for (int m = 32; m >= 1; m >>= 1) v = fmaxf(v, __shfl_xor(v, m));
      if (tid == 0) red2[0] = v;
    }
    __syncthreads();
    if (tid < SS) sc[tid] = __expf(sc[tid] - red2[0]);
    __syncthreads();
    if (tid < 64) {
      float v = sc[tid] + sc[tid + 64];
#pragma unroll
      for (int m = 32; m >= 1; m >>= 1) v += __shfl_xor(v, m);
      if (tid == 0) red2[1] = fast_rcp(v);
    }
    __syncthreads();
    // weighted[e] = sum_s attn[s] * enc_outputs[b,s,e]
    {
      const float rs = red2[1];
      const float* eo = enc_outputs + (size_t)b * (SS * EE);
      float w0 = 0.f, w1 = 0.f;
#pragma unroll 4
      for (int s2 = 0; s2 < SS; ++s2) {
        float a = sc[s2] * rs;
        w0 = fmaf(a, eo[(size_t)s2 * EE + tid], w0);
        w1 = fmaf(a, eo[(size_t)s2 * EE + tid + 512], w1);
      }
      float* wt = wtd_buf + (size_t)(t & 1) * (BB * EE) + (size_t)b * EE;
      wt[tid] = w0;
      wt[tid + 512] = w1;
    }
  } else {
    if (t == 0) return;
    // pred(t-1): out[b, t-1, n] += h_new . fc_W[n,:512] + weighted . fc_W[n,512:1536]
    const int wg = bid - BB;        // 0..191
    const int task = tid >> 2;      // 0..127  -> (n_i, b)
    const int sub = tid & 3;
    const int n = wg * 4 + (task >> 5);
    const int b = task & 31;
    const float* hn = h_buf + (size_t)pp * (BB * HH) + (size_t)b * HH;
    const float* wv = wtd_buf + (size_t)pp * (BB * EE) + (size_t)b * EE;
    const float* fw = fc_W + (size_t)n * CIN;
    float acc = 0.f;
#pragma unroll 4
    for (int k = sub; k < HH; k += 4) acc = fmaf(hn[k], fw[k], acc);
#pragma unroll 4
    for (int k = sub; k < EE; k += 4) acc = fmaf(wv[k], fw[HH + k], acc);
    acc += __shfl_xor(acc, 1);
    acc += __shfl_xor(acc, 2);
    if (sub == 0) out[((size_t)b * TT + (t - 1)) * DD + n] += acc;
  }
}

// ---------------- step2: h_new (gates); 256 blocks own 2 j's each ------------
__global__ __launch_bounds__(512) void step2_kernel(
    int t,
    const float* __restrict__ W_ih,    // (1536, 1792); cols 768.. = weighted part
    const float* __restrict__ W_hh,    // (1536, 512)
    const float* __restrict__ b_hh,    // (1536)
    const float* __restrict__ gi_emb,  // (B,T,1536) = emb@W_ih[:, :768].T + b_ih
    float* __restrict__ h_buf,
    const float* __restrict__ wtd_buf)
{
  __shared__ float smw[2 * 3 * EE];  // W_ih weighted-part rows for j0, j0+1
  __shared__ float smh[2 * 3 * HH];  // W_hh rows
  const int tid = threadIdx.x;
  const int j0 = blockIdx.x * 2;
  for (int idx = tid; idx < 2 * 3 * EE; idx += 512) {
    int jj = idx / (3 * EE);
    int g = (idx / EE) % 3;
    int k = idx % EE;
    smw[idx] = W_ih[(size_t)(g * HH + j0 + jj) * II + DD + k];
  }
  for (int idx = tid; idx < 2 * 3 * HH; idx += 512) {
    int jj = idx / (3 * HH);
    int g = (idx / HH) % 3;
    int k = idx % HH;
    smh[idx] = W_hh[(size_t)(g * HH + j0 + jj) * HH + k];
  }
  __syncthreads();
  const int task = tid >> 3;  // 0..63 -> (jj, b)
  const int sub = tid & 7;
  const int jj = task >> 5;
  const int b = task & 31;
  const int j = j0 + jj;
  const int pp = (t & 1) ^ 1;
  const float* wv = wtd_buf + (size_t)(t & 1) * (BB * EE) + (size_t)b * EE;
  const float* hp = h_buf + (size_t)pp * (BB * HH) + (size_t)b * HH;
  const float* wr = smw + jj * (3 * EE);
  const float* hr = smh + jj * (3 * HH);
  float ar = 0.f, az = 0.f, an = 0.f;
#pragma unroll 4
  for (int k = sub; k < EE; k += 8) {
    float x = wv[k];
    ar = fmaf(x, wr[k], ar);
    az = fmaf(x, wr[EE + k], az);
    an = fmaf(x, wr[2 * EE + k], an);
  }
  float gr = 0.f, gz = 0.f, gn = 0.f;
#pragma unroll 4
  for (int k = sub; k < HH; k += 8) {
    float hh = hp[k];
    gr = fmaf(hh, hr[k], gr);
    gz = fmaf(hh, hr[HH + k], gz);
    gn = fmaf(hh, hr[2 * HH + k], gn);
  }
#pragma unroll
  for (int m = 1; m < 8; m <<= 1) {
    ar += __shfl_xor(ar, m);
    az += __shfl_xor(az, m);
    an += __shfl_xor(an, m);
    gr += __shfl_xor(gr, m);
    gz += __shfl_xor(gz, m);
    gn += __shfl_xor(gn, m);
  }
  if (sub == 0) {
    const float* ge = gi_emb + ((size_t)b * TT + t) * G3;
    float gi_r = ar + ge[j];
    float gi_z = az + ge[HH + j];
    float gi_n = an + ge[2 * HH + j];
    float gh_r = gr + b_hh[j];
    float gh_z = gz + b_hh[HH + j];
    float gh_n = gn + b_hh[2 * HH + j];
    float r = sigmoid_f(gi_r + gh_r);
    float z = sigmoid_f(gi_z + gh_z);
    float nn = tanh_f(gi_n + r * gh_n);
    h_buf[(size_t)(t & 1) * (BB * HH) + (size_t)b * HH + j] =
        (1.f - z) * nn + z * hp[j];
  }
}

extern "C" void kernel_launch(void* const* d_in, const int* in_sizes, int n_in,
                              void* d_out, int out_size, void* d_ws, size_t ws_size,
                              hipStream_t stream) {
  (void)in_sizes; (void)n_in; (void)out_size; (void)ws_size;
  const int* input_ids = (const int*)d_in[0];
  // d_in[1] = attention_mask: all ones by construction -> ids == input_ids
  const float* enc_hidden  = (const float*)d_in[2];
  const float* enc_outputs = (const float*)d_in[3];
  const float* embed_W = (const float*)d_in[4];
  const float* attn_W  = (const float*)d_in[5];
  const float* attn_b  = (const float*)d_in[6];
  const float* val_w   = (const float*)d_in[7];
  const float* W_ih    = (const float*)d_in[8];
  const float* W_hh    = (const float*)d_in[9];
  const float* b_ih    = (const float*)d_in[10];
  const float* b_hh    = (const float*)d_in[11];
  const float* fc_W    = (const float*)d_in[12];
  const float* fc_b    = (const float*)d_in[13];
  float* out = (float*)d_out;

  float* ws = (float*)d_ws;
  float* emb_all  = ws;                               // B*T*D
  float* enc_proj = emb_all + (size_t)BB * TT * DD;   // B*S*H
  float* gi_emb   = enc_proj + (size_t)BB * SS * HH;  // B*T*3H
  float* h_buf    = gi_emb + (size_t)BB * TT * G3;    // 2*B*H
  float* wtd_buf  = h_buf + 2 * BB * HH;              // 2*B*E2

  // ---- precompute (h-independent) ----
  emb_kernel<<<BB * TT, 256, 0, stream>>>(input_ids, embed_W, emb_all);
  copyh_kernel<<<(BB * HH + 511) / 512, 512, 0, stream>>>(enc_hidden, h_buf);
  // enc_proj = enc_outputs @ Wa_e + attn_b
  gemm_ab<<<dim3(HH / BN, (BB * SS) / BM), 256, 0, stream>>>(
      enc_outputs, EE, attn_W + HH * HH, HH, attn_b, enc_proj, HH, EE);
  // gi_emb = emb_all @ W_ih[:, :768]^T + b_ih
  gemm_abt<<<dim3(G3 / BN, (BB * TT) / BM), 256, 0, stream>>>(
      emb_all, DD, W_ih, II, b_ih, gi_emb, G3, DD);
  // out = emb_all @ fc_W[:, 1536:]^T + fc_b   (pred emb-part, accumulated later)
  gemm_abt<<<dim3(DD / BN, (BB * TT) / BM), 256, 0, stream>>>(
      emb_all, DD, fc_W + G3, CIN, fc_b, out, DD, DD);

  // ---- serial recurrence ----
  for (int t = 0; t <= TT; ++t) {
    step1_kernel<<<BB + 192, 512, 0, stream>>>(
        t, attn_W, val_w, enc_outputs, enc_proj, fc_W, h_buf, wtd_buf, out);
    if (t < TT)
      step2_kernel<<<HH / 2, 512, 0, stream>>>(
          t, W_ih, W_hh, b_hh, gi_emb, h_buf, wtd_buf);
  }
}